// Round 10
// baseline (372.623 us; speedup 1.0000x reference)
//
#include <hip/hip_runtime.h>
#include <hip/hip_fp16.h>
#include <cstdint>
#include <cstddef>

#define INF_  128
#define OUTF  64
#define ALPHA 0.2f
#define LN_EPS 1e-5f

#define NB    1024        // coarse buckets (src >> 7)
#define LOCB  7           // 128 local nodes per bucket
#define NBLK  2048        // edge-partition blocks for count/scatter
#define MAXK  32          // finalize register path: covers bucket cnt <= 8192 (64 sigma)
#define SLACK 1024        // per-bucket erec padding slack (128 nodes x 8 max pad)

typedef __attribute__((ext_vector_type(8))) _Float16 half8;
typedef __attribute__((ext_vector_type(4))) float    f32x4;

// ============ phase1: role-split merged kernel ============
// blocks %3==2 -> MFMA gemm (1024 logical blocks); else -> count_coarse (2048).
// Independent work, different pipes (MFMA vs LDS-atomic/mem) -> co-scheduled.
__global__ __launch_bounds__(256) void phase1_kernel(
    const float* __restrict__ x, const float* __restrict__ W,
    const float* __restrict__ b, const float* __restrict__ a,
    __half* __restrict__ hh, float* __restrict__ sl, float* __restrict__ sr, int n,
    const int* __restrict__ src, int* __restrict__ M, int E)
{
    __shared__ __align__(16) char smem[16384];
    const int tid  = threadIdx.x;
    const int role = blockIdx.x % 3;

    if (role == 2) {
        // ---------- MFMA GEMM: wave = 16 nodes x 64 outs ----------
        half8 (*wfrag_lds)[64] = (half8(*)[64])smem;
        const int gid  = blockIdx.x / 3;          // 0..1023
        const int lane = tid & 63;
        const int wv   = tid >> 6;
        const int col  = lane & 15;
        const int quad = lane >> 4;

        for (int idx = tid; idx < 1024; idx += 256) {
            const int l  = idx & 63, ct = idx >> 6;
            const int c  = ct >> 2,  t  = ct & 3;
            const int row = 4 * (l & 15) + t;
            const int k0  = 32 * c + 8 * (l >> 4);
            const float4 f0 = ((const float4*)W)[row * 32 + (k0 >> 2)];
            const float4 f1 = ((const float4*)W)[row * 32 + (k0 >> 2) + 1];
            half8 h;
            h[0] = (_Float16)f0.x; h[1] = (_Float16)f0.y;
            h[2] = (_Float16)f0.z; h[3] = (_Float16)f0.w;
            h[4] = (_Float16)f1.x; h[5] = (_Float16)f1.y;
            h[6] = (_Float16)f1.z; h[7] = (_Float16)f1.w;
            wfrag_lds[ct][l] = h;
        }
        __syncthreads();

        half8 bf[4][4];
        #pragma unroll
        for (int c = 0; c < 4; c++)
            #pragma unroll
            for (int t = 0; t < 4; t++)
                bf[c][t] = wfrag_lds[c * 4 + t][lane];

        const float4 b4  = ((const float4*)b)[col];
        const float4 al4 = ((const float4*)a)[col];
        const float4 ar4 = ((const float4*)a)[16 + col];

        const int ntile  = (n + 15) >> 4;
        const int wgid   = gid * 4 + wv;
        const int nwaves = 1024 * 4;

        for (int tile = wgid; tile < ntile; tile += nwaves) {
            const int node0 = tile << 4;
            const int xr    = min(node0 + col, n - 1);
            const float* xrow = x + (size_t)xr * INF_ + 8 * quad;

            f32x4 acc0 = {0,0,0,0}, acc1 = {0,0,0,0}, acc2 = {0,0,0,0}, acc3 = {0,0,0,0};
            #pragma unroll
            for (int c = 0; c < 4; c++) {
                const float4 f0 = *(const float4*)(xrow + 32 * c);
                const float4 f1 = *(const float4*)(xrow + 32 * c + 4);
                half8 af;
                af[0] = (_Float16)f0.x; af[1] = (_Float16)f0.y;
                af[2] = (_Float16)f0.z; af[3] = (_Float16)f0.w;
                af[4] = (_Float16)f1.x; af[5] = (_Float16)f1.y;
                af[6] = (_Float16)f1.z; af[7] = (_Float16)f1.w;
                acc0 = __builtin_amdgcn_mfma_f32_16x16x32_f16(af, bf[c][0], acc0, 0, 0, 0);
                acc1 = __builtin_amdgcn_mfma_f32_16x16x32_f16(af, bf[c][1], acc1, 0, 0, 0);
                acc2 = __builtin_amdgcn_mfma_f32_16x16x32_f16(af, bf[c][2], acc2, 0, 0, 0);
                acc3 = __builtin_amdgcn_mfma_f32_16x16x32_f16(af, bf[c][3], acc3, 0, 0, 0);
            }

            #pragma unroll
            for (int reg = 0; reg < 4; reg++) {
                const int node = node0 + quad * 4 + reg;
                const float v0 = acc0[reg] + b4.x;
                const float v1 = acc1[reg] + b4.y;
                const float v2 = acc2[reg] + b4.z;
                const float v3 = acc3[reg] + b4.w;
                float p = v0 * al4.x + v1 * al4.y + v2 * al4.z + v3 * al4.w;
                float q = v0 * ar4.x + v1 * ar4.y + v2 * ar4.z + v3 * ar4.w;
                p += __shfl_xor(p, 1); p += __shfl_xor(p, 2);
                p += __shfl_xor(p, 4); p += __shfl_xor(p, 8);
                q += __shfl_xor(q, 1); q += __shfl_xor(q, 2);
                q += __shfl_xor(q, 4); q += __shfl_xor(q, 8);
                if (node < n) {
                    ushort4 u;
                    u.x = __half_as_ushort(__float2half(v0));
                    u.y = __half_as_ushort(__float2half(v1));
                    u.z = __half_as_ushort(__float2half(v2));
                    u.w = __half_as_ushort(__float2half(v3));
                    ((ushort4*)hh)[(size_t)node * 16 + col] = u;
                    if (col == 0) { sl[node] = p; sr[node] = q; }
                }
            }
        }
    } else {
        // ---------- count_coarse: per-block LDS histogram ----------
        int* hist = (int*)smem;
        const int bid = (blockIdx.x / 3) * 2 + role;   // 0..2047
        for (int i = tid; i < NB; i += 256) hist[i] = 0;
        __syncthreads();
        const int chunk = (E + NBLK - 1) / NBLK;
        const int lo = bid * chunk;
        const int hi = min(E, lo + chunk);
        for (int e = lo + tid; e < hi; e += 256)
            atomicAdd(&hist[src[e] >> LOCB], 1);
        __syncthreads();
        for (int i = tid; i < NB; i += 256)
            M[bid * NB + i] = hist[i];
    }
}

// in-place exclusive column prefix (coalesced across lanes); colsum[B]=total
__global__ __launch_bounds__(256) void colscan_kernel(
    int* __restrict__ M, int* __restrict__ colsum)
{
    const int B = blockIdx.x * 256 + (int)threadIdx.x;   // grid NB/256
    int run = 0;
    for (int b = 0; b < NBLK; b += 8) {
        int c[8];
        #pragma unroll
        for (int k = 0; k < 8; k++) c[k] = M[(size_t)(b + k) * NB + B];
        #pragma unroll
        for (int k = 0; k < 8; k++) { M[(size_t)(b + k) * NB + B] = run; run += c[k]; }
    }
    colsum[B] = run;
}

__global__ __launch_bounds__(1024) void scan_bucket(
    const int* __restrict__ colsum, int* __restrict__ bbase)
{
    __shared__ int part[NB];
    const int t = threadIdx.x;
    const int own = colsum[t];
    part[t] = own;
    __syncthreads();
    for (int d = 1; d < NB; d <<= 1) {
        int v = (t >= d) ? part[t - d] : 0;
        __syncthreads();
        part[t] += v;
        __syncthreads();
    }
    bbase[t] = part[t] - own;
    if (t == NB - 1) bbase[NB] = part[t];
}

// slim scatter: coalesced loads -> LDS cursor -> 4B random store.
__global__ __launch_bounds__(256) void scatter_coarse(
    const int* __restrict__ src, const int* __restrict__ dst,
    const int* __restrict__ M, const int* __restrict__ bbase,
    int* __restrict__ pk, int E)
{
    __shared__ int cur[NB];
    for (int i = threadIdx.x; i < NB; i += 256)
        cur[i] = M[blockIdx.x * NB + i] + bbase[i];
    __syncthreads();
    const int chunk = (E + NBLK - 1) / NBLK;
    const int lo = blockIdx.x * chunk;
    const int hi = min(E, lo + chunk);
    for (int e = lo + (int)threadIdx.x; e < hi; e += 256) {
        const int s = src[e];
        const int p = atomicAdd(&cur[s >> LOCB], 1);
        pk[p] = ((s & 127) << 17) | dst[e];      // dst < 2^17
    }
}

// ============ finalize: per-bucket padded CSR with packed edge records ============
// erec[j] = {dst, w(float)}. Per node padded to multiple of 8 with w=0 sentinels ->
// gather runs guard-free. rank captured from the hist atomic (pass-3 plain stores).
__global__ __launch_bounds__(256) void finalize_kernel(
    const int* __restrict__ pk, const int* __restrict__ bbase,
    const float* __restrict__ sl, const float* __restrict__ sr,
    int* __restrict__ off, int* __restrict__ oend, uint2* __restrict__ erec, int n)
{
    __shared__ int   lhist[128];
    __shared__ int   sc[256];
    __shared__ int   lbase[128];
    __shared__ int   cur2[128];
    __shared__ float lsl[128];

    const int B  = blockIdx.x;
    const int b0 = bbase[B];
    const int cnt = bbase[B + 1] - b0;
    const int ebase = b0 + (B << 10);      // per-bucket SLACK for padding
    const int t  = threadIdx.x;

    if (t < 128) {
        lhist[t] = 0;
        const int s = (B << LOCB) + t;
        lsl[t] = (s < n) ? sl[s] : 0.f;
    }
    __syncthreads();

    const int myn = (cnt > t) ? (cnt - t + 255) >> 8 : 0;
    int   pkr[MAXK];
    float wf[MAXK];
    int   rk[MAXK];
    #pragma unroll
    for (int k = 0; k < MAXK; k++) {
        if (k < myn) {
            const int v = pk[b0 + t + (k << 8)];
            pkr[k] = v;
            const int s = (v >> 17) & 127;
            rk[k] = atomicAdd(&lhist[s], 1);              // rank = free byproduct
            const float scv = lsl[s] + sr[v & 0x1FFFF];   // random L2 gather in flight
            const float lr  = scv > 0.f ? scv : ALPHA * scv;
            wf[k] = __expf(-lr);
        }
    }
    for (int k = MAXK; k < myn; k++)
        atomicAdd(&lhist[(pk[b0 + t + (k << 8)] >> 17) & 127], 1);
    const int ovf = __syncthreads_or((int)(myn > MAXK));  // never taken on this graph

    // padded scan: per-node region = (cnt+7)&~7
    const int raw = (t < 128) ? lhist[t] : 0;
    const int pad = (raw + 7) & ~7;
    sc[t] = pad;
    __syncthreads();
    for (int d = 1; d < 256; d <<= 1) {
        int u = (t >= d) ? sc[t - d] : 0;
        __syncthreads();
        sc[t] += u;
        __syncthreads();
    }
    if (t < 128) {
        const int lb = sc[t] - pad;
        lbase[t] = lb;
        cur2[t]  = lb;
        const int s = (B << LOCB) + t;
        if (s < n) { off[s] = ebase + lb; oend[s] = ebase + lb + pad; }
        for (int k = raw; k < pad; k++)                   // w=0 sentinels
            erec[ebase + lb + k] = make_uint2(0u, 0u);
    }
    __syncthreads();

    if (!ovf) {
        #pragma unroll
        for (int k = 0; k < MAXK; k++) {
            if (k < myn) {
                const int s = (pkr[k] >> 17) & 127;
                erec[ebase + lbase[s] + rk[k]] =
                    make_uint2((unsigned)(pkr[k] & 0x1FFFF), __float_as_uint(wf[k]));
            }
        }
    } else {                                              // safe fallback: atomic place
        for (int k = 0; k < myn; k++) {
            const int v = pk[b0 + t + (k << 8)];
            const int s = (v >> 17) & 127, d = v & 0x1FFFF;
            const float scv = lsl[s] + sr[d];
            const float lr  = scv > 0.f ? scv : ALPHA * scv;
            const int p = atomicAdd(&cur2[s], 1);
            erec[ebase + p] = make_uint2((unsigned)d, __float_as_uint(__expf(-lr)));
        }
    }
}

// ==== flat gather + LN + ELU: guard-free inner loop on padded packed records ====
__global__ __launch_bounds__(256) void gather_kernel(
    const __half* __restrict__ hh,
    const int* __restrict__ off, const int* __restrict__ oend,
    const uint2* __restrict__ erec,
    const float* __restrict__ gamma, const float* __restrict__ beta,
    float* __restrict__ out, int n)
{
    const int lane  = threadIdx.x & 63;
    const int fgrp  = lane & 15;
    const int equad = lane >> 4;
    const int wave  = (int)((blockIdx.x * blockDim.x + threadIdx.x) >> 6);
    const int nw    = (int)((gridDim.x * blockDim.x) >> 6);
    const float4 gm4 = ((const float4*)gamma)[fgrp];
    const float4 bt4 = ((const float4*)beta)[fgrp];

    for (int i = wave; i < n; i += nw) {
        const int o0 = off[i], o1 = oend[i];    // o1-o0 multiple of 8
        float4 acc = make_float4(0.f, 0.f, 0.f, 0.f);

        for (int j = o0 + equad; j < o1; j += 8) {
            const uint2 eA = erec[j];           // 16 lanes/address: broadcast
            const uint2 eB = erec[j + 4];
            const float wA = __uint_as_float(eA.y);
            const float wB = __uint_as_float(eB.y);
            const uint2 uA = ((const uint2*)hh)[(size_t)eA.x * 16 + fgrp];
            const uint2 uB = ((const uint2*)hh)[(size_t)eB.x * 16 + fgrp];
            const float2 fA0 = __half22float2(*(const __half2*)&uA.x);
            const float2 fA1 = __half22float2(*(const __half2*)&uA.y);
            const float2 fB0 = __half22float2(*(const __half2*)&uB.x);
            const float2 fB1 = __half22float2(*(const __half2*)&uB.y);
            acc.x = fmaf(wA, fA0.x, acc.x); acc.y = fmaf(wA, fA0.y, acc.y);
            acc.z = fmaf(wA, fA1.x, acc.z); acc.w = fmaf(wA, fA1.y, acc.w);
            acc.x = fmaf(wB, fB0.x, acc.x); acc.y = fmaf(wB, fB0.y, acc.y);
            acc.z = fmaf(wB, fB1.x, acc.z); acc.w = fmaf(wB, fB1.y, acc.w);
        }

        // merge edge-quads (lane bits 4,5)
        acc.x += __shfl_xor(acc.x, 16); acc.x += __shfl_xor(acc.x, 32);
        acc.y += __shfl_xor(acc.y, 16); acc.y += __shfl_xor(acc.y, 32);
        acc.z += __shfl_xor(acc.z, 16); acc.z += __shfl_xor(acc.z, 32);
        acc.w += __shfl_xor(acc.w, 16); acc.w += __shfl_xor(acc.w, 32);

        // LayerNorm (biased var) over 64 features across 16 fgrps
        float s1 = acc.x + acc.y + acc.z + acc.w;
        #pragma unroll
        for (int dd = 1; dd < 16; dd <<= 1) s1 += __shfl_xor(s1, dd);
        const float mu = s1 * (1.f / 64.f);
        const float dx = acc.x - mu, dy = acc.y - mu, dz = acc.z - mu, dw = acc.w - mu;
        float s2 = dx * dx + dy * dy + dz * dz + dw * dw;
        #pragma unroll
        for (int dd = 1; dd < 16; dd <<= 1) s2 += __shfl_xor(s2, dd);
        const float rs = rsqrtf(s2 * (1.f / 64.f) + LN_EPS);

        float4 y;
        y.x = dx * rs * gm4.x + bt4.x;
        y.y = dy * rs * gm4.y + bt4.y;
        y.z = dz * rs * gm4.z + bt4.z;
        y.w = dw * rs * gm4.w + bt4.w;
        y.x = y.x > 0.f ? y.x : expm1f(y.x);
        y.y = y.y > 0.f ? y.y : expm1f(y.y);
        y.z = y.z > 0.f ? y.z : expm1f(y.z);
        y.w = y.w > 0.f ? y.w : expm1f(y.w);
        if (equad == 0)
            ((float4*)out)[(size_t)i * 16 + fgrp] = y;
    }
}

// ---------------- launch ----------------
extern "C" void kernel_launch(void* const* d_in, const int* in_sizes, int n_in,
                              void* d_out, int out_size, void* d_ws, size_t ws_size,
                              hipStream_t stream)
{
    const float* x     = (const float*)d_in[0];
    const int*   edge  = (const int*)  d_in[1];
    const float* W     = (const float*)d_in[2];
    const float* b     = (const float*)d_in[3];
    const float* a     = (const float*)d_in[4];
    const float* gamma = (const float*)d_in[5];
    const float* beta  = (const float*)d_in[6];
    float* out = (float*)d_out;

    const int n = in_sizes[0] / INF_;   // 100000
    const int E = in_sizes[1] / 2;      // 3200000
    const int* src = edge;
    const int* dst = edge + E;
    const int nbuck = (n + 127) >> 7;   // 782 buckets

    char* ws = (char*)d_ws;
    size_t offb = 0;
    auto alloc = [&](size_t bytes) -> void* {
        void* p = ws + offb;
        offb = (offb + bytes + 255) & ~(size_t)255;
        return p;
    };
    __half* hh    = (__half*)alloc((size_t)n * OUTF * 2);
    float*  sl    = (float*) alloc((size_t)n * 4);
    float*  sr    = (float*) alloc((size_t)n * 4);
    int*    M     = (int*)   alloc((size_t)NBLK * NB * 4);   // 8 MB
    int*    colsum= (int*)   alloc((size_t)NB * 4);
    int*    bbase = (int*)   alloc((size_t)(NB + 1) * 4);
    int*    off   = (int*)   alloc((size_t)n * 4);
    int*    oend  = (int*)   alloc((size_t)n * 4);
    int*    pk    = (int*)   alloc((size_t)E * 4);
    uint2*  erec  = (uint2*) alloc(((size_t)E + (size_t)NB * SLACK) * 8);  // ~34 MB

    hipLaunchKernelGGL(phase1_kernel,   dim3(3072),   dim3(256),  0, stream,
                       x, W, b, a, hh, sl, sr, n, src, M, E);
    hipLaunchKernelGGL(colscan_kernel,  dim3(NB/256), dim3(256),  0, stream, M, colsum);
    hipLaunchKernelGGL(scan_bucket,     dim3(1),      dim3(1024), 0, stream, colsum, bbase);
    hipLaunchKernelGGL(scatter_coarse,  dim3(NBLK),   dim3(256),  0, stream, src, dst, M, bbase, pk, E);
    hipLaunchKernelGGL(finalize_kernel, dim3(nbuck),  dim3(256),  0, stream, pk, bbase, sl, sr, off, oend, erec, n);
    hipLaunchKernelGGL(gather_kernel,   dim3(4096),   dim3(256),  0, stream, hh, off, oend, erec, gamma, beta, out, n);
}

// Round 11
// 286.355 us; speedup vs baseline: 1.3013x; 1.3013x over previous
//
#include <hip/hip_runtime.h>
#include <hip/hip_fp16.h>
#include <cstdint>
#include <cstddef>

#define INF_  128
#define OUTF  64
#define ALPHA 0.2f
#define LN_EPS 1e-5f

#define NB    1024        // coarse buckets (src >> 7)
#define LOCB  7           // 128 local nodes per bucket
#define NBLK  2048        // edge-partition blocks for count/scatter
#define NSTR  16          // stripes for parallel column scan (NBLK/NSTR = 128 rows)
#define MAXK  24          // finalize register path (bucket cnt <= 6144 = mean+32sigma)

typedef __attribute__((ext_vector_type(8))) _Float16 half8;
typedef __attribute__((ext_vector_type(4))) float    f32x4;

// ---------------- MFMA GEMM: h(fp16) = x @ W^T + b, sl = h@a_l, sr = h@a_r ----
__global__ __launch_bounds__(256) void gemm_kernel(
    const float* __restrict__ x, const float* __restrict__ W,
    const float* __restrict__ b, const float* __restrict__ a,
    __half* __restrict__ hh, float* __restrict__ sl, float* __restrict__ sr, int n)
{
    __shared__ half8 wfrag_lds[16][64];   // 16 KB

    const int tid  = threadIdx.x;
    const int lane = tid & 63;
    const int wv   = tid >> 6;
    const int col  = lane & 15;
    const int quad = lane >> 4;

    for (int idx = tid; idx < 1024; idx += 256) {
        const int l  = idx & 63, ct = idx >> 6;
        const int c  = ct >> 2,  t  = ct & 3;
        const int row = 4 * (l & 15) + t;
        const int k0  = 32 * c + 8 * (l >> 4);
        const float4 f0 = ((const float4*)W)[row * 32 + (k0 >> 2)];
        const float4 f1 = ((const float4*)W)[row * 32 + (k0 >> 2) + 1];
        half8 h;
        h[0] = (_Float16)f0.x; h[1] = (_Float16)f0.y;
        h[2] = (_Float16)f0.z; h[3] = (_Float16)f0.w;
        h[4] = (_Float16)f1.x; h[5] = (_Float16)f1.y;
        h[6] = (_Float16)f1.z; h[7] = (_Float16)f1.w;
        wfrag_lds[ct][l] = h;
    }
    __syncthreads();

    half8 bf[4][4];
    #pragma unroll
    for (int c = 0; c < 4; c++)
        #pragma unroll
        for (int t = 0; t < 4; t++)
            bf[c][t] = wfrag_lds[c * 4 + t][lane];

    const float4 b4  = ((const float4*)b)[col];
    const float4 al4 = ((const float4*)a)[col];
    const float4 ar4 = ((const float4*)a)[16 + col];

    const int ntile  = (n + 15) >> 4;
    const int wgid   = blockIdx.x * 4 + wv;
    const int nwaves = gridDim.x * 4;

    for (int tile = wgid; tile < ntile; tile += nwaves) {
        const int node0 = tile << 4;
        const int xr    = min(node0 + col, n - 1);
        const float* xrow = x + (size_t)xr * INF_ + 8 * quad;

        f32x4 acc0 = {0,0,0,0}, acc1 = {0,0,0,0}, acc2 = {0,0,0,0}, acc3 = {0,0,0,0};
        #pragma unroll
        for (int c = 0; c < 4; c++) {
            const float4 f0 = *(const float4*)(xrow + 32 * c);
            const float4 f1 = *(const float4*)(xrow + 32 * c + 4);
            half8 af;
            af[0] = (_Float16)f0.x; af[1] = (_Float16)f0.y;
            af[2] = (_Float16)f0.z; af[3] = (_Float16)f0.w;
            af[4] = (_Float16)f1.x; af[5] = (_Float16)f1.y;
            af[6] = (_Float16)f1.z; af[7] = (_Float16)f1.w;
            acc0 = __builtin_amdgcn_mfma_f32_16x16x32_f16(af, bf[c][0], acc0, 0, 0, 0);
            acc1 = __builtin_amdgcn_mfma_f32_16x16x32_f16(af, bf[c][1], acc1, 0, 0, 0);
            acc2 = __builtin_amdgcn_mfma_f32_16x16x32_f16(af, bf[c][2], acc2, 0, 0, 0);
            acc3 = __builtin_amdgcn_mfma_f32_16x16x32_f16(af, bf[c][3], acc3, 0, 0, 0);
        }

        #pragma unroll
        for (int reg = 0; reg < 4; reg++) {
            const int node = node0 + quad * 4 + reg;
            const float v0 = acc0[reg] + b4.x;
            const float v1 = acc1[reg] + b4.y;
            const float v2 = acc2[reg] + b4.z;
            const float v3 = acc3[reg] + b4.w;
            float p = v0 * al4.x + v1 * al4.y + v2 * al4.z + v3 * al4.w;
            float q = v0 * ar4.x + v1 * ar4.y + v2 * ar4.z + v3 * ar4.w;
            p += __shfl_xor(p, 1); p += __shfl_xor(p, 2);
            p += __shfl_xor(p, 4); p += __shfl_xor(p, 8);
            q += __shfl_xor(q, 1); q += __shfl_xor(q, 2);
            q += __shfl_xor(q, 4); q += __shfl_xor(q, 8);
            if (node < n) {
                ushort4 u;
                u.x = __half_as_ushort(__float2half(v0));
                u.y = __half_as_ushort(__float2half(v1));
                u.z = __half_as_ushort(__float2half(v2));
                u.w = __half_as_ushort(__float2half(v3));
                ((ushort4*)hh)[(size_t)node * 16 + col] = u;
                if (col == 0) { sl[node] = p; sr[node] = q; }
            }
        }
    }
}

// ---------------- count: per-block LDS histogram, int4 edge loads ----------------
__global__ __launch_bounds__(256) void count_coarse(
    const int* __restrict__ src, int* __restrict__ M, int E)
{
    __shared__ int hist[NB];
    for (int i = threadIdx.x; i < NB; i += 256) hist[i] = 0;
    __syncthreads();
    const int chunk = (((E + NBLK - 1) / NBLK) + 3) & ~3;
    const int lo = blockIdx.x * chunk;
    const int hi = min(E, lo + chunk);
    for (int e = lo + (int)threadIdx.x * 4; e < hi; e += 1024) {
        if (e + 3 < hi) {
            const int4 s4 = *(const int4*)(src + e);
            atomicAdd(&hist[s4.x >> LOCB], 1);
            atomicAdd(&hist[s4.y >> LOCB], 1);
            atomicAdd(&hist[s4.z >> LOCB], 1);
            atomicAdd(&hist[s4.w >> LOCB], 1);
        } else {
            for (int k = e; k < hi; k++) atomicAdd(&hist[src[k] >> LOCB], 1);
        }
    }
    __syncthreads();
    for (int i = threadIdx.x; i < NB; i += 256)
        M[blockIdx.x * NB + i] = hist[i];
}

// ---- parallel column scan of M (NBLK x NB), stripe-hierarchical ----
// A: 64 blocks produce stripe sums S[s][B]
__global__ __launch_bounds__(256) void colscan_a(
    const int* __restrict__ M, int* __restrict__ S)
{
    const int s  = blockIdx.x >> 2;
    const int B  = (blockIdx.x & 3) * 256 + (int)threadIdx.x;
    const int r0 = s * (NBLK / NSTR);
    int sum = 0;
    for (int r = 0; r < NBLK / NSTR; r += 8) {
        int c[8];
        #pragma unroll
        for (int k = 0; k < 8; k++) c[k] = M[(size_t)(r0 + r + k) * NB + B];
        #pragma unroll
        for (int k = 0; k < 8; k++) sum += c[k];
    }
    S[s * NB + B] = sum;
}

// B: 1 block: per-column stripe scan + cross-column bucket scan, bbase out,
//    S[s][B] <- bbase[B] + exclusive-stripe-prefix (so scatter needs no bbase add)
__global__ __launch_bounds__(1024) void colscan_b(
    int* __restrict__ S, int* __restrict__ bbase)
{
    __shared__ int part[NB];
    const int t = threadIdx.x;           // = column B
    int st[NSTR];
    int run = 0;
    #pragma unroll
    for (int s = 0; s < NSTR; s++) {
        const int c = S[s * NB + t];
        st[s] = run; run += c;
    }
    part[t] = run;                       // colsum
    __syncthreads();
    for (int d = 1; d < NB; d <<= 1) {
        int v = (t >= d) ? part[t - d] : 0;
        __syncthreads();
        part[t] += v;
        __syncthreads();
    }
    const int bb = part[t] - run;        // exclusive bucket base
    bbase[t] = bb;
    if (t == NB - 1) bbase[NB] = part[t];
    #pragma unroll
    for (int s = 0; s < NSTR; s++) S[s * NB + t] = bb + st[s];
}

// C: 64 blocks: M[b][B] <- global exclusive prefix (incl. bbase)
__global__ __launch_bounds__(256) void colscan_c(
    int* __restrict__ M, const int* __restrict__ S)
{
    const int s  = blockIdx.x >> 2;
    const int B  = (blockIdx.x & 3) * 256 + (int)threadIdx.x;
    const int r0 = s * (NBLK / NSTR);
    int run = S[s * NB + B];
    for (int r = 0; r < NBLK / NSTR; r += 8) {
        int c[8];
        #pragma unroll
        for (int k = 0; k < 8; k++) c[k] = M[(size_t)(r0 + r + k) * NB + B];
        #pragma unroll
        for (int k = 0; k < 8; k++) { M[(size_t)(r0 + r + k) * NB + B] = run; run += c[k]; }
    }
}

// slim scatter: int4 edge loads -> LDS cursor -> 4B random store.
__global__ __launch_bounds__(256) void scatter_coarse(
    const int* __restrict__ src, const int* __restrict__ dst,
    const int* __restrict__ M, int* __restrict__ pk, int E)
{
    __shared__ int cur[NB];
    for (int i = threadIdx.x; i < NB; i += 256)
        cur[i] = M[blockIdx.x * NB + i];             // already includes bbase
    __syncthreads();
    const int chunk = (((E + NBLK - 1) / NBLK) + 3) & ~3;
    const int lo = blockIdx.x * chunk;
    const int hi = min(E, lo + chunk);
    for (int e = lo + (int)threadIdx.x * 4; e < hi; e += 1024) {
        if (e + 3 < hi) {
            const int4 s4 = *(const int4*)(src + e);
            const int4 d4 = *(const int4*)(dst + e);
            int p;
            p = atomicAdd(&cur[s4.x >> LOCB], 1); pk[p] = ((s4.x & 127) << 17) | d4.x;
            p = atomicAdd(&cur[s4.y >> LOCB], 1); pk[p] = ((s4.y & 127) << 17) | d4.y;
            p = atomicAdd(&cur[s4.z >> LOCB], 1); pk[p] = ((s4.z & 127) << 17) | d4.z;
            p = atomicAdd(&cur[s4.w >> LOCB], 1); pk[p] = ((s4.w & 127) << 17) | d4.w;
        } else {
            for (int k = e; k < hi; k++) {
                const int s = src[k];
                const int p = atomicAdd(&cur[s >> LOCB], 1);
                pk[p] = ((s & 127) << 17) | dst[k];
            }
        }
    }
}

// ---------------- finalize: per-bucket local CSR + edge weights ----------------
// rank captured from the hist atomic (pass 3 = plain stores, single atomic storm).
__global__ __launch_bounds__(256) void finalize_kernel(
    const int* __restrict__ pk, const int* __restrict__ bbase,
    const float* __restrict__ sl, const float* __restrict__ sr,
    int* __restrict__ off, int* __restrict__ bdst, __half* __restrict__ wgt,
    int n, int E)
{
    __shared__ int   lhist[128];
    __shared__ int   sc[256];
    __shared__ int   lbase[128];
    __shared__ int   cur2[128];
    __shared__ float lsl[128];

    const int B  = blockIdx.x;
    const int b0 = bbase[B];
    const int cnt = bbase[B + 1] - b0;
    const int t  = threadIdx.x;

    if (t < 128) {
        lhist[t] = 0;
        const int s = (B << LOCB) + t;
        lsl[t] = (s < n) ? sl[s] : 0.f;
    }
    __syncthreads();

    const int myn = (cnt > t) ? (cnt - t + 255) >> 8 : 0;
    int   pkr[MAXK];
    float wf[MAXK];
    int   rk[MAXK];
    #pragma unroll
    for (int k = 0; k < MAXK; k++) {
        if (k < myn) {
            const int v = pk[b0 + t + (k << 8)];
            pkr[k] = v;
            const int s = (v >> 17) & 127;
            rk[k] = atomicAdd(&lhist[s], 1);              // rank = free byproduct
            const float scv = lsl[s] + sr[v & 0x1FFFF];   // random L2 gather in flight
            const float lr  = scv > 0.f ? scv : ALPHA * scv;
            wf[k] = __expf(-lr);
        }
    }
    for (int k = MAXK; k < myn; k++)
        atomicAdd(&lhist[(pk[b0 + t + (k << 8)] >> 17) & 127], 1);
    const int ovf = __syncthreads_or((int)(myn > MAXK));  // never taken on this graph

    const int v = (t < 128) ? lhist[t] : 0;
    sc[t] = v;
    __syncthreads();
    for (int d = 1; d < 256; d <<= 1) {
        int u = (t >= d) ? sc[t - d] : 0;
        __syncthreads();
        sc[t] += u;
        __syncthreads();
    }
    if (t < 128) {
        const int base = b0 + sc[t] - v;     // global exclusive
        lbase[t] = base;
        cur2[t]  = base;
        const int s = (B << LOCB) + t;
        if (s < n) off[s] = base;
    }
    if (B == 0 && t == 0) off[n] = E;
    __syncthreads();

    if (!ovf) {
        #pragma unroll
        for (int k = 0; k < MAXK; k++) {
            if (k < myn) {
                const int s = (pkr[k] >> 17) & 127;
                const int p = lbase[s] + rk[k];           // exact slot, no atomic
                bdst[p] = pkr[k] & 0x1FFFF;
                wgt[p]  = __float2half(wf[k]);
            }
        }
    } else {                                              // safe fallback
        for (int k = 0; k < myn; k++) {
            const int w = pk[b0 + t + (k << 8)];
            const int s = (w >> 17) & 127, d = w & 0x1FFFF;
            const float scv = lsl[s] + sr[d];
            const float lr  = scv > 0.f ? scv : ALPHA * scv;
            const int p = atomicAdd(&cur2[s], 1);
            bdst[p] = d;
            wgt[p]  = __float2half(__expf(-lr));
        }
    }
}

// ---- flat gather + LN + ELU (R9 form): chunk-prologue loads + shfl broadcast ----
__global__ __launch_bounds__(256) void gather_kernel(
    const __half* __restrict__ hh,
    const int* __restrict__ off, const int* __restrict__ bdst,
    const __half* __restrict__ wgt,
    const float* __restrict__ gamma, const float* __restrict__ beta,
    float* __restrict__ out, int n)
{
    const int lane  = threadIdx.x & 63;
    const int fgrp  = lane & 15;
    const int equad = lane >> 4;
    const int wave  = (int)((blockIdx.x * blockDim.x + threadIdx.x) >> 6);
    const int nw    = (int)((gridDim.x * blockDim.x) >> 6);
    const float4 gm4 = ((const float4*)gamma)[fgrp];
    const float4 bt4 = ((const float4*)beta)[fgrp];

    for (int i = wave; i < n; i += nw) {
        const int o0 = off[i], o1 = off[i + 1];
        float4 acc = make_float4(0.f, 0.f, 0.f, 0.f);

        for (int base = o0; base < o1; base += 64) {
            const int j = base + lane;
            int d = 0; float w = 0.f;
            if (j < o1) { d = bdst[j]; w = __half2float(wgt[j]); }
            const int m = min(64, o1 - base);

            for (int t = 0; t < m; t += 8) {
                const int e0 = t + equad, e1 = t + 4 + equad;
                int   dd0 = __shfl(d, e0); float ww0 = __shfl(w, e0);
                int   dd1 = __shfl(d, e1); float ww1 = __shfl(w, e1);
                if (e0 >= m) { dd0 = 0; ww0 = 0.f; }
                if (e1 >= m) { dd1 = 0; ww1 = 0.f; }
                const uint2 u0 = ((const uint2*)hh)[(size_t)dd0 * 16 + fgrp];
                const uint2 u1 = ((const uint2*)hh)[(size_t)dd1 * 16 + fgrp];
                const float2 f00 = __half22float2(*(const __half2*)&u0.x);
                const float2 f01 = __half22float2(*(const __half2*)&u0.y);
                const float2 f10 = __half22float2(*(const __half2*)&u1.x);
                const float2 f11 = __half22float2(*(const __half2*)&u1.y);
                acc.x = fmaf(ww0, f00.x, acc.x); acc.y = fmaf(ww0, f00.y, acc.y);
                acc.z = fmaf(ww0, f01.x, acc.z); acc.w = fmaf(ww0, f01.y, acc.w);
                acc.x = fmaf(ww1, f10.x, acc.x); acc.y = fmaf(ww1, f10.y, acc.y);
                acc.z = fmaf(ww1, f11.x, acc.z); acc.w = fmaf(ww1, f11.y, acc.w);
            }
        }

        acc.x += __shfl_xor(acc.x, 16); acc.x += __shfl_xor(acc.x, 32);
        acc.y += __shfl_xor(acc.y, 16); acc.y += __shfl_xor(acc.y, 32);
        acc.z += __shfl_xor(acc.z, 16); acc.z += __shfl_xor(acc.z, 32);
        acc.w += __shfl_xor(acc.w, 16); acc.w += __shfl_xor(acc.w, 32);

        float s1 = acc.x + acc.y + acc.z + acc.w;
        #pragma unroll
        for (int dd = 1; dd < 16; dd <<= 1) s1 += __shfl_xor(s1, dd);
        const float mu = s1 * (1.f / 64.f);
        const float dx = acc.x - mu, dy = acc.y - mu, dz = acc.z - mu, dw = acc.w - mu;
        float s2 = dx * dx + dy * dy + dz * dz + dw * dw;
        #pragma unroll
        for (int dd = 1; dd < 16; dd <<= 1) s2 += __shfl_xor(s2, dd);
        const float rs = rsqrtf(s2 * (1.f / 64.f) + LN_EPS);

        float4 y;
        y.x = dx * rs * gm4.x + bt4.x;
        y.y = dy * rs * gm4.y + bt4.y;
        y.z = dz * rs * gm4.z + bt4.z;
        y.w = dw * rs * gm4.w + bt4.w;
        y.x = y.x > 0.f ? y.x : __expf(y.x) - 1.f;   // ELU via fast exp
        y.y = y.y > 0.f ? y.y : __expf(y.y) - 1.f;
        y.z = y.z > 0.f ? y.z : __expf(y.z) - 1.f;
        y.w = y.w > 0.f ? y.w : __expf(y.w) - 1.f;
        if (equad == 0)
            ((float4*)out)[(size_t)i * 16 + fgrp] = y;
    }
}

// ---------------- launch ----------------
extern "C" void kernel_launch(void* const* d_in, const int* in_sizes, int n_in,
                              void* d_out, int out_size, void* d_ws, size_t ws_size,
                              hipStream_t stream)
{
    const float* x     = (const float*)d_in[0];
    const int*   edge  = (const int*)  d_in[1];
    const float* W     = (const float*)d_in[2];
    const float* b     = (const float*)d_in[3];
    const float* a     = (const float*)d_in[4];
    const float* gamma = (const float*)d_in[5];
    const float* beta  = (const float*)d_in[6];
    float* out = (float*)d_out;

    const int n = in_sizes[0] / INF_;   // 100000
    const int E = in_sizes[1] / 2;      // 3200000
    const int* src = edge;
    const int* dst = edge + E;
    const int nbuck = (n + 127) >> 7;   // 782 buckets

    char* ws = (char*)d_ws;
    size_t offb = 0;
    auto alloc = [&](size_t bytes) -> void* {
        void* p = ws + offb;
        offb = (offb + bytes + 255) & ~(size_t)255;
        return p;
    };
    __half* hh    = (__half*)alloc((size_t)n * OUTF * 2);
    float*  sl    = (float*) alloc((size_t)n * 4);
    float*  sr    = (float*) alloc((size_t)n * 4);
    int*    M     = (int*)   alloc((size_t)NBLK * NB * 4);   // 8 MB
    int*    S     = (int*)   alloc((size_t)NSTR * NB * 4);   // 64 KB stripe sums
    int*    bbase = (int*)   alloc((size_t)(NB + 1) * 4);
    int*    off   = (int*)   alloc((size_t)(n + 1) * 4);
    int*    pk    = (int*)   alloc((size_t)E * 4);
    int*    bdst  = (int*)   alloc((size_t)E * 4);
    __half* wgt   = (__half*)alloc((size_t)E * 2);

    hipLaunchKernelGGL(count_coarse,    dim3(NBLK),  dim3(256),  0, stream, src, M, E);
    hipLaunchKernelGGL(colscan_a,       dim3(64),    dim3(256),  0, stream, M, S);
    hipLaunchKernelGGL(colscan_b,       dim3(1),     dim3(1024), 0, stream, S, bbase);
    hipLaunchKernelGGL(colscan_c,       dim3(64),    dim3(256),  0, stream, M, S);
    hipLaunchKernelGGL(gemm_kernel,     dim3(1024),  dim3(256),  0, stream, x, W, b, a, hh, sl, sr, n);
    hipLaunchKernelGGL(scatter_coarse,  dim3(NBLK),  dim3(256),  0, stream, src, dst, M, pk, E);
    hipLaunchKernelGGL(finalize_kernel, dim3(nbuck), dim3(256),  0, stream, pk, bbase, sl, sr, off, bdst, wgt, n, E);
    hipLaunchKernelGGL(gather_kernel,   dim3(4096),  dim3(256),  0, stream, hh, off, bdst, wgt, gamma, beta, out, n);
}

// Round 12
// 279.903 us; speedup vs baseline: 1.3313x; 1.0231x over previous
//
#include <hip/hip_runtime.h>
#include <hip/hip_fp16.h>
#include <cstdint>
#include <cstddef>

#define INF_  128
#define OUTF  64
#define ALPHA 0.2f
#define LN_EPS 1e-5f

#define NB    1024        // coarse buckets (src >> 7)
#define LOCB  7           // 128 local nodes per bucket
#define NBLK  1024        // edge chunks/blocks: 1024*64KB/8XCD ~ L2-sized write window
#define NSTR  16          // stripes for parallel column scan (NBLK/NSTR = 64 rows)
#define MAXK  24          // finalize register path (bucket cnt <= 6144 = mean+32sigma)

typedef __attribute__((ext_vector_type(8))) _Float16 half8;
typedef __attribute__((ext_vector_type(4))) float    f32x4;

// ---------------- MFMA GEMM: h(fp16) = x @ W^T + b, sl = h@a_l, sr = h@a_r ----
__global__ __launch_bounds__(256) void gemm_kernel(
    const float* __restrict__ x, const float* __restrict__ W,
    const float* __restrict__ b, const float* __restrict__ a,
    __half* __restrict__ hh, float* __restrict__ sl, float* __restrict__ sr, int n)
{
    __shared__ half8 wfrag_lds[16][64];   // 16 KB

    const int tid  = threadIdx.x;
    const int lane = tid & 63;
    const int wv   = tid >> 6;
    const int col  = lane & 15;
    const int quad = lane >> 4;

    for (int idx = tid; idx < 1024; idx += 256) {
        const int l  = idx & 63, ct = idx >> 6;
        const int c  = ct >> 2,  t  = ct & 3;
        const int row = 4 * (l & 15) + t;
        const int k0  = 32 * c + 8 * (l >> 4);
        const float4 f0 = ((const float4*)W)[row * 32 + (k0 >> 2)];
        const float4 f1 = ((const float4*)W)[row * 32 + (k0 >> 2) + 1];
        half8 h;
        h[0] = (_Float16)f0.x; h[1] = (_Float16)f0.y;
        h[2] = (_Float16)f0.z; h[3] = (_Float16)f0.w;
        h[4] = (_Float16)f1.x; h[5] = (_Float16)f1.y;
        h[6] = (_Float16)f1.z; h[7] = (_Float16)f1.w;
        wfrag_lds[ct][l] = h;
    }
    __syncthreads();

    half8 bf[4][4];
    #pragma unroll
    for (int c = 0; c < 4; c++)
        #pragma unroll
        for (int t = 0; t < 4; t++)
            bf[c][t] = wfrag_lds[c * 4 + t][lane];

    const float4 b4  = ((const float4*)b)[col];
    const float4 al4 = ((const float4*)a)[col];
    const float4 ar4 = ((const float4*)a)[16 + col];

    const int ntile  = (n + 15) >> 4;
    const int wgid   = blockIdx.x * 4 + wv;
    const int nwaves = gridDim.x * 4;

    for (int tile = wgid; tile < ntile; tile += nwaves) {
        const int node0 = tile << 4;
        const int xr    = min(node0 + col, n - 1);
        const float* xrow = x + (size_t)xr * INF_ + 8 * quad;

        f32x4 acc0 = {0,0,0,0}, acc1 = {0,0,0,0}, acc2 = {0,0,0,0}, acc3 = {0,0,0,0};
        #pragma unroll
        for (int c = 0; c < 4; c++) {
            const float4 f0 = *(const float4*)(xrow + 32 * c);
            const float4 f1 = *(const float4*)(xrow + 32 * c + 4);
            half8 af;
            af[0] = (_Float16)f0.x; af[1] = (_Float16)f0.y;
            af[2] = (_Float16)f0.z; af[3] = (_Float16)f0.w;
            af[4] = (_Float16)f1.x; af[5] = (_Float16)f1.y;
            af[6] = (_Float16)f1.z; af[7] = (_Float16)f1.w;
            acc0 = __builtin_amdgcn_mfma_f32_16x16x32_f16(af, bf[c][0], acc0, 0, 0, 0);
            acc1 = __builtin_amdgcn_mfma_f32_16x16x32_f16(af, bf[c][1], acc1, 0, 0, 0);
            acc2 = __builtin_amdgcn_mfma_f32_16x16x32_f16(af, bf[c][2], acc2, 0, 0, 0);
            acc3 = __builtin_amdgcn_mfma_f32_16x16x32_f16(af, bf[c][3], acc3, 0, 0, 0);
        }

        #pragma unroll
        for (int reg = 0; reg < 4; reg++) {
            const int node = node0 + quad * 4 + reg;
            const float v0 = acc0[reg] + b4.x;
            const float v1 = acc1[reg] + b4.y;
            const float v2 = acc2[reg] + b4.z;
            const float v3 = acc3[reg] + b4.w;
            float p = v0 * al4.x + v1 * al4.y + v2 * al4.z + v3 * al4.w;
            float q = v0 * ar4.x + v1 * ar4.y + v2 * ar4.z + v3 * ar4.w;
            p += __shfl_xor(p, 1); p += __shfl_xor(p, 2);
            p += __shfl_xor(p, 4); p += __shfl_xor(p, 8);
            q += __shfl_xor(q, 1); q += __shfl_xor(q, 2);
            q += __shfl_xor(q, 4); q += __shfl_xor(q, 8);
            if (node < n) {
                ushort4 u;
                u.x = __half_as_ushort(__float2half(v0));
                u.y = __half_as_ushort(__float2half(v1));
                u.z = __half_as_ushort(__float2half(v2));
                u.w = __half_as_ushort(__float2half(v3));
                ((ushort4*)hh)[(size_t)node * 16 + col] = u;
                if (col == 0) { sl[node] = p; sr[node] = q; }
            }
        }
    }
}

// ---------------- count: per-block LDS histogram, 8-edge ILP ----------------
__global__ __launch_bounds__(256) void count_coarse(
    const int* __restrict__ src, int* __restrict__ M, int E)
{
    __shared__ int hist[NB];
    for (int i = threadIdx.x; i < NB; i += 256) hist[i] = 0;
    __syncthreads();
    const int chunk = (((E + NBLK - 1) / NBLK) + 7) & ~7;
    const int lo = blockIdx.x * chunk;
    const int hi = min(E, lo + chunk);
    for (int e = lo + (int)threadIdx.x * 8; e < hi; e += 2048) {
        if (e + 7 < hi) {
            const int4 a4 = *(const int4*)(src + e);
            const int4 c4 = *(const int4*)(src + e + 4);
            atomicAdd(&hist[a4.x >> LOCB], 1);
            atomicAdd(&hist[a4.y >> LOCB], 1);
            atomicAdd(&hist[a4.z >> LOCB], 1);
            atomicAdd(&hist[a4.w >> LOCB], 1);
            atomicAdd(&hist[c4.x >> LOCB], 1);
            atomicAdd(&hist[c4.y >> LOCB], 1);
            atomicAdd(&hist[c4.z >> LOCB], 1);
            atomicAdd(&hist[c4.w >> LOCB], 1);
        } else {
            for (int k = e; k < hi; k++) atomicAdd(&hist[src[k] >> LOCB], 1);
        }
    }
    __syncthreads();
    for (int i = threadIdx.x; i < NB; i += 256)
        M[blockIdx.x * NB + i] = hist[i];
}

// ---- parallel column scan of M (NBLK x NB), stripe-hierarchical ----
__global__ __launch_bounds__(256) void colscan_a(
    const int* __restrict__ M, int* __restrict__ S)
{
    const int s  = blockIdx.x >> 2;
    const int B  = (blockIdx.x & 3) * 256 + (int)threadIdx.x;
    const int r0 = s * (NBLK / NSTR);
    int sum = 0;
    for (int r = 0; r < NBLK / NSTR; r += 8) {
        int c[8];
        #pragma unroll
        for (int k = 0; k < 8; k++) c[k] = M[(size_t)(r0 + r + k) * NB + B];
        #pragma unroll
        for (int k = 0; k < 8; k++) sum += c[k];
    }
    S[s * NB + B] = sum;
}

__global__ __launch_bounds__(1024) void colscan_b(
    int* __restrict__ S, int* __restrict__ bbase)
{
    __shared__ int part[NB];
    const int t = threadIdx.x;           // = column B
    int st[NSTR];
    int run = 0;
    #pragma unroll
    for (int s = 0; s < NSTR; s++) {
        const int c = S[s * NB + t];
        st[s] = run; run += c;
    }
    part[t] = run;
    __syncthreads();
    for (int d = 1; d < NB; d <<= 1) {
        int v = (t >= d) ? part[t - d] : 0;
        __syncthreads();
        part[t] += v;
        __syncthreads();
    }
    const int bb = part[t] - run;
    bbase[t] = bb;
    if (t == NB - 1) bbase[NB] = part[t];
    #pragma unroll
    for (int s = 0; s < NSTR; s++) S[s * NB + t] = bb + st[s];
}

__global__ __launch_bounds__(256) void colscan_c(
    int* __restrict__ M, const int* __restrict__ S)
{
    const int s  = blockIdx.x >> 2;
    const int B  = (blockIdx.x & 3) * 256 + (int)threadIdx.x;
    const int r0 = s * (NBLK / NSTR);
    int run = S[s * NB + B];
    for (int r = 0; r < NBLK / NSTR; r += 8) {
        int c[8];
        #pragma unroll
        for (int k = 0; k < 8; k++) c[k] = M[(size_t)(r0 + r + k) * NB + B];
        #pragma unroll
        for (int k = 0; k < 8; k++) { M[(size_t)(r0 + r + k) * NB + B] = run; run += c[k]; }
    }
}

// slim scatter: 8-edge ILP -> LDS cursor -> 4B random store (cursors incl. bbase)
__global__ __launch_bounds__(256) void scatter_coarse(
    const int* __restrict__ src, const int* __restrict__ dst,
    const int* __restrict__ M, int* __restrict__ pk, int E)
{
    __shared__ int cur[NB];
    for (int i = threadIdx.x; i < NB; i += 256)
        cur[i] = M[blockIdx.x * NB + i];
    __syncthreads();
    const int chunk = (((E + NBLK - 1) / NBLK) + 7) & ~7;
    const int lo = blockIdx.x * chunk;
    const int hi = min(E, lo + chunk);
    for (int e = lo + (int)threadIdx.x * 8; e < hi; e += 2048) {
        if (e + 7 < hi) {
            const int4 s4 = *(const int4*)(src + e);
            const int4 t4 = *(const int4*)(src + e + 4);
            const int4 d4 = *(const int4*)(dst + e);
            const int4 u4 = *(const int4*)(dst + e + 4);
            int p;
            p = atomicAdd(&cur[s4.x >> LOCB], 1); pk[p] = ((s4.x & 127) << 17) | d4.x;
            p = atomicAdd(&cur[s4.y >> LOCB], 1); pk[p] = ((s4.y & 127) << 17) | d4.y;
            p = atomicAdd(&cur[s4.z >> LOCB], 1); pk[p] = ((s4.z & 127) << 17) | d4.z;
            p = atomicAdd(&cur[s4.w >> LOCB], 1); pk[p] = ((s4.w & 127) << 17) | d4.w;
            p = atomicAdd(&cur[t4.x >> LOCB], 1); pk[p] = ((t4.x & 127) << 17) | u4.x;
            p = atomicAdd(&cur[t4.y >> LOCB], 1); pk[p] = ((t4.y & 127) << 17) | u4.y;
            p = atomicAdd(&cur[t4.z >> LOCB], 1); pk[p] = ((t4.z & 127) << 17) | u4.z;
            p = atomicAdd(&cur[t4.w >> LOCB], 1); pk[p] = ((t4.w & 127) << 17) | u4.w;
        } else {
            for (int k = e; k < hi; k++) {
                const int s = src[k];
                const int p = atomicAdd(&cur[s >> LOCB], 1);
                pk[p] = ((s & 127) << 17) | dst[k];
            }
        }
    }
}

// ---------------- finalize: per-bucket local CSR + edge weights ----------------
__global__ __launch_bounds__(256) void finalize_kernel(
    const int* __restrict__ pk, const int* __restrict__ bbase,
    const float* __restrict__ sl, const float* __restrict__ sr,
    int* __restrict__ off, int* __restrict__ bdst, __half* __restrict__ wgt,
    int n, int E)
{
    __shared__ int   lhist[128];
    __shared__ int   sc[256];
    __shared__ int   lbase[128];
    __shared__ int   cur2[128];
    __shared__ float lsl[128];

    const int B  = blockIdx.x;
    const int b0 = bbase[B];
    const int cnt = bbase[B + 1] - b0;
    const int t  = threadIdx.x;

    if (t < 128) {
        lhist[t] = 0;
        const int s = (B << LOCB) + t;
        lsl[t] = (s < n) ? sl[s] : 0.f;
    }
    __syncthreads();

    const int myn = (cnt > t) ? (cnt - t + 255) >> 8 : 0;
    int   pkr[MAXK];
    float wf[MAXK];
    int   rk[MAXK];
    #pragma unroll
    for (int k = 0; k < MAXK; k++) {
        if (k < myn) {
            const int v = pk[b0 + t + (k << 8)];
            pkr[k] = v;
            const int s = (v >> 17) & 127;
            rk[k] = atomicAdd(&lhist[s], 1);
            const float scv = lsl[s] + sr[v & 0x1FFFF];
            const float lr  = scv > 0.f ? scv : ALPHA * scv;
            wf[k] = __expf(-lr);
        }
    }
    for (int k = MAXK; k < myn; k++)
        atomicAdd(&lhist[(pk[b0 + t + (k << 8)] >> 17) & 127], 1);
    const int ovf = __syncthreads_or((int)(myn > MAXK));

    const int v = (t < 128) ? lhist[t] : 0;
    sc[t] = v;
    __syncthreads();
    for (int d = 1; d < 256; d <<= 1) {
        int u = (t >= d) ? sc[t - d] : 0;
        __syncthreads();
        sc[t] += u;
        __syncthreads();
    }
    if (t < 128) {
        const int base = b0 + sc[t] - v;
        lbase[t] = base;
        cur2[t]  = base;
        const int s = (B << LOCB) + t;
        if (s < n) off[s] = base;
    }
    if (B == 0 && t == 0) off[n] = E;
    __syncthreads();

    if (!ovf) {
        #pragma unroll
        for (int k = 0; k < MAXK; k++) {
            if (k < myn) {
                const int s = (pkr[k] >> 17) & 127;
                const int p = lbase[s] + rk[k];
                bdst[p] = pkr[k] & 0x1FFFF;
                wgt[p]  = __float2half(wf[k]);
            }
        }
    } else {
        for (int k = 0; k < myn; k++) {
            const int w = pk[b0 + t + (k << 8)];
            const int s = (w >> 17) & 127, d = w & 0x1FFFF;
            const float scv = lsl[s] + sr[d];
            const float lr  = scv > 0.f ? scv : ALPHA * scv;
            const int p = atomicAdd(&cur2[s], 1);
            bdst[p] = d;
            wgt[p]  = __float2half(__expf(-lr));
        }
    }
}

// ---- gather + LN + ELU: software-pipelined inner loop + cross-node prefetch ----
__global__ __launch_bounds__(256) void gather_kernel(
    const __half* __restrict__ hh,
    const int* __restrict__ off, const int* __restrict__ bdst,
    const __half* __restrict__ wgt,
    const float* __restrict__ gamma, const float* __restrict__ beta,
    float* __restrict__ out, int n)
{
    const int lane  = threadIdx.x & 63;
    const int fgrp  = lane & 15;
    const int equad = lane >> 4;
    const int wave  = (int)((blockIdx.x * blockDim.x + threadIdx.x) >> 6);
    const int nw    = (int)((gridDim.x * blockDim.x) >> 6);
    const float4 gm4 = ((const float4*)gamma)[fgrp];
    const float4 bt4 = ((const float4*)beta)[fgrp];

    int i = wave;
    int co0 = 0, co1 = 0;
    int dpre = 0; float wpre = 0.f;
    if (i < n) {
        co0 = off[i]; co1 = off[i + 1];
        const int j = co0 + lane;
        if (j < co1) { dpre = bdst[j]; wpre = __half2float(wgt[j]); }
    }

    for (; i < n; i += nw) {
        const int o0 = co0, o1 = co1;
        int d = dpre; float w = wpre;

        const int inext = i + nw;
        if (inext < n) { co0 = off[inext]; co1 = off[inext + 1]; }  // early issue

        float4 acc = make_float4(0.f, 0.f, 0.f, 0.f);

        for (int base = o0; base < o1; base += 64) {
            if (base != o0) {                       // chunk 0 was prefetched
                const int j = base + lane;
                d = 0; w = 0.f;
                if (j < o1) { d = bdst[j]; w = __half2float(wgt[j]); }
            }
            const int m = min(64, o1 - base);

            // group 0 loads issued up front; each iter issues group g+1 before
            // consuming group g -> 4 hh loads in flight per wave
            {
                const int e0 = equad, e1 = 4 + equad;
                int dd0 = __shfl(d, e0); float ww0 = __shfl(w, e0);
                int dd1 = __shfl(d, e1); float ww1 = __shfl(w, e1);
                if (e0 >= m) { dd0 = 0; ww0 = 0.f; }
                if (e1 >= m) { dd1 = 0; ww1 = 0.f; }
                uint2 uA = ((const uint2*)hh)[(size_t)dd0 * 16 + fgrp];
                uint2 uB = ((const uint2*)hh)[(size_t)dd1 * 16 + fgrp];
                float wA = ww0, wB = ww1;

                for (int t = 0; t < m; t += 8) {
                    uint2 nA = make_uint2(0u, 0u), nB = make_uint2(0u, 0u);
                    float nwA = 0.f, nwB = 0.f;
                    if (t + 8 < m) {
                        const int f0 = t + 8 + equad, f1 = t + 12 + equad;
                        int x0 = __shfl(d, f0); nwA = __shfl(w, f0);
                        int x1 = __shfl(d, f1); nwB = __shfl(w, f1);
                        if (f0 >= m) { x0 = 0; nwA = 0.f; }
                        if (f1 >= m) { x1 = 0; nwB = 0.f; }
                        nA = ((const uint2*)hh)[(size_t)x0 * 16 + fgrp];
                        nB = ((const uint2*)hh)[(size_t)x1 * 16 + fgrp];
                    }
                    const float2 fA0 = __half22float2(*(const __half2*)&uA.x);
                    const float2 fA1 = __half22float2(*(const __half2*)&uA.y);
                    const float2 fB0 = __half22float2(*(const __half2*)&uB.x);
                    const float2 fB1 = __half22float2(*(const __half2*)&uB.y);
                    acc.x = fmaf(wA, fA0.x, acc.x); acc.y = fmaf(wA, fA0.y, acc.y);
                    acc.z = fmaf(wA, fA1.x, acc.z); acc.w = fmaf(wA, fA1.y, acc.w);
                    acc.x = fmaf(wB, fB0.x, acc.x); acc.y = fmaf(wB, fB0.y, acc.y);
                    acc.z = fmaf(wB, fB1.x, acc.z); acc.w = fmaf(wB, fB1.y, acc.w);
                    uA = nA; uB = nB; wA = nwA; wB = nwB;
                }
            }
        }

        // prefetch next node's first chunk (latency hidden by LN tail)
        dpre = 0; wpre = 0.f;
        if (inext < n) {
            const int j = co0 + lane;
            if (j < co1) { dpre = bdst[j]; wpre = __half2float(wgt[j]); }
        }

        // merge edge-quads (lane bits 4,5)
        acc.x += __shfl_xor(acc.x, 16); acc.x += __shfl_xor(acc.x, 32);
        acc.y += __shfl_xor(acc.y, 16); acc.y += __shfl_xor(acc.y, 32);
        acc.z += __shfl_xor(acc.z, 16); acc.z += __shfl_xor(acc.z, 32);
        acc.w += __shfl_xor(acc.w, 16); acc.w += __shfl_xor(acc.w, 32);

        // one-pass LN: sum + sumsq in interleaved shfl chains; var = E[x^2]-mu^2
        float s1 = acc.x + acc.y + acc.z + acc.w;
        float s2 = acc.x * acc.x + acc.y * acc.y + acc.z * acc.z + acc.w * acc.w;
        #pragma unroll
        for (int dd = 1; dd < 16; dd <<= 1) {
            s1 += __shfl_xor(s1, dd);
            s2 += __shfl_xor(s2, dd);
        }
        const float mu  = s1 * (1.f / 64.f);
        const float var = fmaxf(s2 * (1.f / 64.f) - mu * mu, 0.f);
        const float rs  = rsqrtf(var + LN_EPS);

        float4 y;
        y.x = (acc.x - mu) * rs * gm4.x + bt4.x;
        y.y = (acc.y - mu) * rs * gm4.y + bt4.y;
        y.z = (acc.z - mu) * rs * gm4.z + bt4.z;
        y.w = (acc.w - mu) * rs * gm4.w + bt4.w;
        y.x = y.x > 0.f ? y.x : __expf(y.x) - 1.f;
        y.y = y.y > 0.f ? y.y : __expf(y.y) - 1.f;
        y.z = y.z > 0.f ? y.z : __expf(y.z) - 1.f;
        y.w = y.w > 0.f ? y.w : __expf(y.w) - 1.f;
        if (equad == 0)
            ((float4*)out)[(size_t)i * 16 + fgrp] = y;
    }
}

// ---------------- launch ----------------
extern "C" void kernel_launch(void* const* d_in, const int* in_sizes, int n_in,
                              void* d_out, int out_size, void* d_ws, size_t ws_size,
                              hipStream_t stream)
{
    const float* x     = (const float*)d_in[0];
    const int*   edge  = (const int*)  d_in[1];
    const float* W     = (const float*)d_in[2];
    const float* b     = (const float*)d_in[3];
    const float* a     = (const float*)d_in[4];
    const float* gamma = (const float*)d_in[5];
    const float* beta  = (const float*)d_in[6];
    float* out = (float*)d_out;

    const int n = in_sizes[0] / INF_;   // 100000
    const int E = in_sizes[1] / 2;      // 3200000
    const int* src = edge;
    const int* dst = edge + E;
    const int nbuck = (n + 127) >> 7;   // 782 buckets

    char* ws = (char*)d_ws;
    size_t offb = 0;
    auto alloc = [&](size_t bytes) -> void* {
        void* p = ws + offb;
        offb = (offb + bytes + 255) & ~(size_t)255;
        return p;
    };
    __half* hh    = (__half*)alloc((size_t)n * OUTF * 2);
    float*  sl    = (float*) alloc((size_t)n * 4);
    float*  sr    = (float*) alloc((size_t)n * 4);
    int*    M     = (int*)   alloc((size_t)NBLK * NB * 4);   // 4 MB
    int*    S     = (int*)   alloc((size_t)NSTR * NB * 4);   // 64 KB stripe sums
    int*    bbase = (int*)   alloc((size_t)(NB + 1) * 4);
    int*    off   = (int*)   alloc((size_t)(n + 1) * 4);
    int*    pk    = (int*)   alloc((size_t)E * 4);
    int*    bdst  = (int*)   alloc((size_t)E * 4);
    __half* wgt   = (__half*)alloc((size_t)E * 2);

    hipLaunchKernelGGL(count_coarse,    dim3(NBLK),  dim3(256),  0, stream, src, M, E);
    hipLaunchKernelGGL(colscan_a,       dim3(64),    dim3(256),  0, stream, M, S);
    hipLaunchKernelGGL(colscan_b,       dim3(1),     dim3(1024), 0, stream, S, bbase);
    hipLaunchKernelGGL(colscan_c,       dim3(64),    dim3(256),  0, stream, M, S);
    hipLaunchKernelGGL(gemm_kernel,     dim3(1024),  dim3(256),  0, stream, x, W, b, a, hh, sl, sr, n);
    hipLaunchKernelGGL(scatter_coarse,  dim3(NBLK),  dim3(256),  0, stream, src, dst, M, pk, E);
    hipLaunchKernelGGL(finalize_kernel, dim3(nbuck), dim3(256),  0, stream, pk, bbase, sl, sr, off, bdst, wgt, n, E);
    hipLaunchKernelGGL(gather_kernel,   dim3(4096),  dim3(256),  0, stream, hh, off, bdst, wgt, gamma, beta, out, n);
}